// Round 10
// baseline (539.144 us; speedup 1.0000x reference)
//
#include <hip/hip_runtime.h>

typedef __attribute__((ext_vector_type(8))) short bf16x8;
typedef __attribute__((ext_vector_type(4))) float f32x4;
typedef __attribute__((ext_vector_type(4))) float f4v;

#define NU 150000
#define NI 50000
#define NTOT 200000
#define KU 524
#define KUP 576
#define KI 1292
#define KIP 1344

__device__ __forceinline__ f4v ld4(const float* p) { return *(const f4v*)p; }

__device__ __forceinline__ unsigned short bf16r(float x) {
    unsigned u = __float_as_uint(x);
    u += 0x7fff + ((u >> 16) & 1);
    return (unsigned short)(u >> 16);
}
__device__ __forceinline__ unsigned pk2(float lo, float hi) {
    unsigned a = __float_as_uint(lo), b = __float_as_uint(hi);
    a += 0x7fff + ((a >> 16) & 1);
    b += 0x7fff + ((b >> 16) & 1);
    return (a >> 16) | (b & 0xffff0000u);
}
__device__ __forceinline__ float bfu(unsigned short u) {
    return __uint_as_float((unsigned)u << 16);
}

// W [K][64] fp32 -> WT [64][Kpad] bf16 (zero-padded K)
__global__ void prep_wt(const float* __restrict__ src, unsigned short* __restrict__ dst,
                        int K, int Kpad) {
    const int c = blockIdx.y;
    const int k = blockIdx.x * 256 + threadIdx.x;
    if (k >= Kpad) return;
    dst[(size_t)c * Kpad + k] = (k < K) ? bf16r(src[(size_t)k * 64 + c]) : (unsigned short)0;
}

// ---------------------------------------------------------------------------
// Text-mean pre-pass, wave-per-node layout (R8, proven). One gather instr
// covers 2 complete 128B word_emb rows => 2 line requests/instr.
// ---------------------------------------------------------------------------
__global__ __launch_bounds__(256, 8) void txt_mean_kernel(
    const float* __restrict__ word_emb,
    const int* __restrict__ u_text_idx, const int* __restrict__ i_text_idx,
    unsigned short* __restrict__ stage)
{
    __shared__ __align__(16) unsigned short st[4][96];   // contiguous 768B
    const int wid  = threadIdx.x >> 6;
    const int lane = threadIdx.x & 63;
    const int node = blockIdx.x * 4 + wid;               // grid exact: NTOT/4
    const int c = lane & 31, h = lane >> 5;
    const int* tip = (node < NU) ? (u_text_idx + (size_t)node * 24)
                                 : (i_text_idx + (size_t)(node - NU) * 24);
    float s[3];
    #pragma unroll
    for (int f = 0; f < 3; ++f) {
        float a = 0.f;
        #pragma unroll
        for (int rr = 0; rr < 4; ++rr) {
            const int idx = tip[f * 8 + rr * 2 + h];     // 32-lane broadcast load
            a += word_emb[(size_t)idx * 32 + c];         // half-wave = full row
        }
        s[f] = a;
    }
    #pragma unroll
    for (int f = 0; f < 3; ++f) s[f] += __shfl_xor(s[f], 32, 64);
    if (h == 0) {
        #pragma unroll
        for (int f = 0; f < 3; ++f) st[wid][f * 32 + c] = bf16r(s[f] * 0.125f);
    }
    __syncthreads();
    // block = 4 consecutive nodes = 768B contiguous: 48 threads x uint4
    if (threadIdx.x < 48) {
        const uint4 v = *(const uint4*)&st[0][threadIdx.x * 8];
        *(uint4*)(stage + (size_t)blockIdx.x * 384 + threadIdx.x * 8) = v;
    }
}

// ---------------------------------------------------------------------------
// Node-feature build + projection, BARRIER-FREE k-loop. Each lane builds its
// MFMA A-fragment directly from global (row = l15, k-span = ki*32+hi8):
// no LDS A-tile, no per-tile barriers, register double-buffer lookahead.
// All segment boundaries are 4-aligned so a per-4-float loader is exact.
// ---------------------------------------------------------------------------
__global__ __launch_bounds__(256, 8) void node_init_kernel(
    const float* __restrict__ id_emb, const float* __restrict__ feat_table,
    const unsigned short* __restrict__ txt_stage, const float* __restrict__ numeric,
    const float* __restrict__ wordvec, const float* __restrict__ sentence,
    const int* __restrict__ feat_idx,
    const unsigned short* __restrict__ WT, const float* __restrict__ projb,
    const float* __restrict__ numW, const float* __restrict__ numb,
    unsigned short* __restrict__ x_out, int n, int Ktot, int Kpad, int row_off)
{
    __shared__ unsigned short fiS[64][5];
    __shared__ float nmrS[64][10];

    const int t = threadIdx.x;
    const int row0 = blockIdx.x * 64;

    for (int e = t; e < 64 * 5; e += 256) {
        const int r = e / 5, j = e - r * 5, row = row0 + r;
        fiS[r][j] = (row < n) ? (unsigned short)feat_idx[row * 5 + j] : (unsigned short)0;
    }
    for (int e = t; e < 64 * 10; e += 256) {
        const int r = e / 10, j = e - r * 10, row = row0 + r;
        nmrS[r][j] = (row < n) ? numeric[(size_t)row * 10 + j] : 0.f;
    }
    __syncthreads();

    const int lane = t & 63;
    const int w16 = (t >> 6) * 16;
    const int l15 = lane & 15;
    const int hi8 = (lane >> 4) * 8;
    const int g4  = (lane >> 4) * 4;

    const int lr   = w16 + l15;          // this lane's A-row (block-local)
    const int lrow = row0 + lr;
    const bool rvalid = lrow < n;
    const size_t gnode = (size_t)(row_off + lrow);

    f32x4 acc[4];
    #pragma unroll
    for (int ct = 0; ct < 4; ++ct) acc[ct] = (f32x4){0.f, 0.f, 0.f, 0.f};

    // per-lane fragment loader: 8 floats at k-span [kb, kb+8)
    auto load_frag = [&](int kb) -> bf16x8 {
        float v[8];
        #pragma unroll
        for (int h = 0; h < 2; ++h) {
            const int k4 = kb + h * 4;
            f4v x = (f4v){0.f, 0.f, 0.f, 0.f};
            if (rvalid && k4 < Ktot) {
                if (k4 >= 524) {
                    x = ld4(sentence + (size_t)lrow * 768 + (k4 - 524));
                } else if (k4 >= 224) {
                    x = ld4(wordvec + (size_t)lrow * 300 + (k4 - 224));
                } else if (k4 >= 128) {
                    const ushort4 q = *(const ushort4*)(txt_stage + gnode * 96 + (k4 - 128));
                    x.x = bfu(q.x); x.y = bfu(q.y); x.z = bfu(q.z); x.w = bfu(q.w);
                } else if (k4 >= 64) {
                    const int c = k4 - 64;
                    f4v s = (f4v){0.f, 0.f, 0.f, 0.f};
                    #pragma unroll
                    for (int m = 0; m < 5; ++m) {
                        const f4v g = ld4(feat_table + (size_t)fiS[lr][m] * 64 + c);
                        s.x += g.x; s.y += g.y; s.z += g.z; s.w += g.w;
                    }
                    x.x = s.x * 0.2f; x.y = s.y * 0.2f;
                    x.z = s.z * 0.2f; x.w = s.w * 0.2f;
                } else {
                    x = ld4(id_emb + (size_t)lrow * 64 + k4);
                }
            }
            v[h * 4 + 0] = x.x; v[h * 4 + 1] = x.y;
            v[h * 4 + 2] = x.z; v[h * 4 + 3] = x.w;
        }
        union { unsigned u[4]; bf16x8 b; } cv;
        cv.u[0] = pk2(v[0], v[1]); cv.u[1] = pk2(v[2], v[3]);
        cv.u[2] = pk2(v[4], v[5]); cv.u[3] = pk2(v[6], v[7]);
        return cv.b;
    };

    const int NK = Kpad / 32;
    bf16x8 af = load_frag(hi8);
    for (int ki = 0; ki < NK; ++ki) {
        bf16x8 afn = af;
        if (ki + 1 < NK) afn = load_frag((ki + 1) * 32 + hi8);
        #pragma unroll
        for (int ct = 0; ct < 4; ++ct) {
            const bf16x8 bfr = *(const bf16x8*)&WT[(size_t)(ct * 16 + l15) * Kpad
                                                  + ki * 32 + hi8];
            acc[ct] = __builtin_amdgcn_mfma_f32_16x16x32_bf16(af, bfr, acc[ct], 0, 0, 0);
        }
        af = afn;
    }

    // epilogue: proj bias + numeric side-GEMM + num bias, write bf16 (cached)
    #pragma unroll
    for (int ct = 0; ct < 4; ++ct) {
        const int c = ct * 16 + l15;
        const float pb = projb[c] + numb[c];
        float wn[10];
        #pragma unroll
        for (int m = 0; m < 10; ++m) wn[m] = numW[m * 64 + c];
        #pragma unroll
        for (int j = 0; j < 4; ++j) {
            const int r = w16 + g4 + j;
            const int row = row0 + r;
            if (row < n) {
                float s = acc[ct][j] + pb;
                #pragma unroll
                for (int m = 0; m < 10; ++m) s += nmrS[r][m] * wn[m];
                x_out[(size_t)(row_off + row) * 64 + c] = bf16r(s);
            }
        }
    }
}

// ---------------------------------------------------------------------------
// GNN layer via MFMA. 64 rows/block. (unchanged; off the top-5)
// ---------------------------------------------------------------------------
__global__ __launch_bounds__(256, 6) void gnn_layer_kernel(
    const unsigned short* __restrict__ x, const int* __restrict__ nbr,
    const unsigned short* __restrict__ VT, const unsigned short* __restrict__ W2T,
    const float* __restrict__ vb, const float* __restrict__ wb,
    void* __restrict__ outp, int finalize)
{
    __shared__ __align__(16) unsigned short mS[64][72];
    __shared__ int nbs[64][8];
    const int t = threadIdx.x;
    const int row0 = blockIdx.x * 64;

    for (int e = t; e < 512; e += 256) nbs[e >> 3][e & 7] = nbr[row0 * 8 + e];
    __syncthreads();

    {   // neighbor mean -> mS (bf16)
        const int r = t >> 2, c16 = (t & 3) * 16;
        float s[16];
        #pragma unroll
        for (int i = 0; i < 16; ++i) s[i] = 0.f;
        #pragma unroll
        for (int m = 0; m < 8; ++m) {
            const unsigned short* p = x + (size_t)nbs[r][m] * 64 + c16;
            const uint4 q0 = *(const uint4*)p;
            const uint4 q1 = *(const uint4*)(p + 8);
            s[0] += bfu(q0.x & 0xffff); s[1] += bfu(q0.x >> 16);
            s[2] += bfu(q0.y & 0xffff); s[3] += bfu(q0.y >> 16);
            s[4] += bfu(q0.z & 0xffff); s[5] += bfu(q0.z >> 16);
            s[6] += bfu(q0.w & 0xffff); s[7] += bfu(q0.w >> 16);
            s[8] += bfu(q1.x & 0xffff); s[9] += bfu(q1.x >> 16);
            s[10] += bfu(q1.y & 0xffff); s[11] += bfu(q1.y >> 16);
            s[12] += bfu(q1.z & 0xffff); s[13] += bfu(q1.z >> 16);
            s[14] += bfu(q1.w & 0xffff); s[15] += bfu(q1.w >> 16);
        }
        uint4 o0, o1;
        o0.x = pk2(s[0] * 0.125f, s[1] * 0.125f);
        o0.y = pk2(s[2] * 0.125f, s[3] * 0.125f);
        o0.z = pk2(s[4] * 0.125f, s[5] * 0.125f);
        o0.w = pk2(s[6] * 0.125f, s[7] * 0.125f);
        o1.x = pk2(s[8] * 0.125f, s[9] * 0.125f);
        o1.y = pk2(s[10] * 0.125f, s[11] * 0.125f);
        o1.z = pk2(s[12] * 0.125f, s[13] * 0.125f);
        o1.w = pk2(s[14] * 0.125f, s[15] * 0.125f);
        *(uint4*)&mS[r][c16] = o0;
        *(uint4*)&mS[r][c16 + 8] = o1;
    }
    __syncthreads();

    const int lane = t & 63;
    const int w16 = (t >> 6) * 16;
    const int l15 = lane & 15;
    const int hi8 = (lane >> 4) * 8;
    const int g4  = (lane >> 4) * 4;

    // agg = nm @ vW
    f32x4 ag[4];
    #pragma unroll
    for (int ct = 0; ct < 4; ++ct) ag[ct] = (f32x4){0.f, 0.f, 0.f, 0.f};
    #pragma unroll
    for (int ks = 0; ks < 2; ++ks) {
        const bf16x8 af = *(const bf16x8*)&mS[w16 + l15][ks * 32 + hi8];
        #pragma unroll
        for (int ct = 0; ct < 4; ++ct) {
            const bf16x8 bfr = *(const bf16x8*)&VT[(ct * 16 + l15) * 64 + ks * 32 + hi8];
            ag[ct] = __builtin_amdgcn_mfma_f32_16x16x32_bf16(af, bfr, ag[ct], 0, 0, 0);
        }
    }
    __syncthreads();   // nm readers done
    #pragma unroll
    for (int ct = 0; ct < 4; ++ct) {
        const int c = ct * 16 + l15;
        const float b = vb[c];
        #pragma unroll
        for (int j = 0; j < 4; ++j)
            mS[w16 + g4 + j][c] = bf16r(ag[ct][j] + b);
    }
    __syncthreads();

    // out = [x | ag] @ wW
    f32x4 acc[4];
    #pragma unroll
    for (int ct = 0; ct < 4; ++ct) acc[ct] = (f32x4){0.f, 0.f, 0.f, 0.f};
    #pragma unroll
    for (int ks = 0; ks < 4; ++ks) {
        bf16x8 af;
        if (ks < 2) af = *(const bf16x8*)&x[(size_t)(row0 + w16 + l15) * 64 + ks * 32 + hi8];
        else        af = *(const bf16x8*)&mS[w16 + l15][(ks - 2) * 32 + hi8];
        #pragma unroll
        for (int ct = 0; ct < 4; ++ct) {
            const bf16x8 bfr = *(const bf16x8*)&W2T[(ct * 16 + l15) * 128 + ks * 32 + hi8];
            acc[ct] = __builtin_amdgcn_mfma_f32_16x16x32_bf16(af, bfr, acc[ct], 0, 0, 0);
        }
    }

    if (!finalize) {
        unsigned short* xo = (unsigned short*)outp;
        #pragma unroll
        for (int ct = 0; ct < 4; ++ct) {
            const int c = ct * 16 + l15;
            const float b = wb[c];
            #pragma unroll
            for (int j = 0; j < 4; ++j)
                xo[(size_t)(row0 + w16 + g4 + j) * 64 + c] = bf16r(fmaxf(acc[ct][j] + b, 0.f));
        }
    } else {
        float* fo = (float*)outp;
        float vc[4][4], ss[4];
        #pragma unroll
        for (int j = 0; j < 4; ++j) ss[j] = 0.f;
        #pragma unroll
        for (int ct = 0; ct < 4; ++ct) {
            const float b = wb[ct * 16 + l15];
            #pragma unroll
            for (int j = 0; j < 4; ++j) {
                vc[ct][j] = acc[ct][j] + b;
                ss[j] += vc[ct][j] * vc[ct][j];
            }
        }
        #pragma unroll
        for (int m = 1; m < 16; m <<= 1) {
            #pragma unroll
            for (int j = 0; j < 4; ++j) ss[j] += __shfl_xor(ss[j], m, 64);
        }
        #pragma unroll
        for (int j = 0; j < 4; ++j) ss[j] = 1.f / fmaxf(sqrtf(ss[j]), 1e-12f);
        #pragma unroll
        for (int ct = 0; ct < 4; ++ct) {
            const int c = ct * 16 + l15;
            #pragma unroll
            for (int j = 0; j < 4; ++j)
                fo[(size_t)(row0 + w16 + g4 + j) * 64 + c] = vc[ct][j] * ss[j];
        }
    }
}

extern "C" void kernel_launch(void* const* d_in, const int* in_sizes, int n_in,
                              void* d_out, int out_size, void* d_ws, size_t ws_size,
                              hipStream_t stream) {
    const float* user_id_emb        = (const float*)d_in[0];
    const float* item_id_emb        = (const float*)d_in[1];
    const float* user_feat_table    = (const float*)d_in[2];
    const float* item_feat_table    = (const float*)d_in[3];
    const float* word_emb           = (const float*)d_in[4];
    const float* user_numeric       = (const float*)d_in[5];
    const float* item_numeric       = (const float*)d_in[6];
    const float* user_word_embedding= (const float*)d_in[7];
    const float* item_word_embedding= (const float*)d_in[8];
    const float* item_sentence_emb  = (const float*)d_in[9];
    const float* user_num_W         = (const float*)d_in[10];
    const float* user_num_b         = (const float*)d_in[11];
    const float* item_num_W         = (const float*)d_in[12];
    const float* item_num_b         = (const float*)d_in[13];
    const float* user_proj_W        = (const float*)d_in[14];
    const float* user_proj_b        = (const float*)d_in[15];
    const float* item_proj_W        = (const float*)d_in[16];
    const float* item_proj_b        = (const float*)d_in[17];
    const float* w_W                = (const float*)d_in[18];
    const float* w_b                = (const float*)d_in[19];
    const float* v_W                = (const float*)d_in[20];
    const float* v_b                = (const float*)d_in[21];
    const int*   user_feat_idx      = (const int*)d_in[22];
    const int*   item_feat_idx      = (const int*)d_in[23];
    const int*   user_text_idx      = (const int*)d_in[24];
    const int*   item_text_idx      = (const int*)d_in[25];
    const int*   neighbors          = (const int*)d_in[26];

    // ws layout (bf16): x0 [NTOT][64], x1 [NTOT][64]
    unsigned short* x0 = (unsigned short*)d_ws;
    unsigned short* x1 = x0 + (size_t)NTOT * 64;

    // d_out FRONT: text-mean staging [NTOT][96] bf16 (38.4 MB, consumed by
    // node_init before the final layer overwrites d_out)
    unsigned short* txt_stage = (unsigned short*)d_out;
    // d_out TAIL: bf16 weights (R3-proven placement, 270 KB)
    const size_t prep_bytes = 2ull * 64 * (KUP + KIP + 64 + 128);
    char* WTbase = (char*)d_out + (size_t)out_size * 4 - prep_bytes;
    unsigned short* WTu = (unsigned short*)WTbase;
    unsigned short* WTi = WTu + 64 * KUP;
    unsigned short* VT0 = WTi + 64 * KIP;
    unsigned short* W20 = VT0 + 64 * 64;
    // layer-1 weights re-prepped into dead x0 region after L0
    unsigned short* VT1 = (unsigned short*)d_ws;
    unsigned short* W21 = VT1 + 64 * 64;

    prep_wt<<<dim3((KUP + 255) / 256, 64), 256, 0, stream>>>(user_proj_W, WTu, KU, KUP);
    prep_wt<<<dim3((KIP + 255) / 256, 64), 256, 0, stream>>>(item_proj_W, WTi, KI, KIP);
    prep_wt<<<dim3(1, 64), 256, 0, stream>>>(v_W, VT0, 64, 64);
    prep_wt<<<dim3(1, 64), 256, 0, stream>>>(w_W, W20, 128, 128);

    // text-mean pre-pass (wave-per-node coalesced gather)
    txt_mean_kernel<<<NTOT / 4, 256, 0, stream>>>(
        word_emb, user_text_idx, item_text_idx, txt_stage);

    node_init_kernel<<<(NU + 63) / 64, 256, 0, stream>>>(
        user_id_emb, user_feat_table, txt_stage, user_numeric,
        user_word_embedding, nullptr, user_feat_idx,
        WTu, user_proj_b, user_num_W, user_num_b, x0, NU, KU, KUP, 0);
    node_init_kernel<<<(NI + 63) / 64, 256, 0, stream>>>(
        item_id_emb, item_feat_table, txt_stage, item_numeric,
        item_word_embedding, item_sentence_emb, item_feat_idx,
        WTi, item_proj_b, item_num_W, item_num_b, x0, NI, KI, KIP, NU);

    // layer 0: x0 -> x1 (relu, bf16)
    gnn_layer_kernel<<<NTOT / 64, 256, 0, stream>>>(
        x0, neighbors, VT0, W20, v_b, w_b, x1, 0);

    // re-prep layer-1 weights into dead x0 region
    prep_wt<<<dim3(1, 64), 256, 0, stream>>>(v_W + 64 * 64, VT1, 64, 64);
    prep_wt<<<dim3(1, 64), 256, 0, stream>>>(w_W + 128 * 64, W21, 128, 128);

    // layer 1 + fused normalize: x1 -> d_out (fp32, overwrites staging+weights)
    gnn_layer_kernel<<<NTOT / 64, 256, 0, stream>>>(
        x1, neighbors, VT1, W21, v_b + 64, w_b + 64, d_out, 1);
}

// Round 11
// 492.095 us; speedup vs baseline: 1.0956x; 1.0956x over previous
//
#include <hip/hip_runtime.h>

typedef __attribute__((ext_vector_type(8))) short bf16x8;
typedef __attribute__((ext_vector_type(4))) float f32x4;
typedef __attribute__((ext_vector_type(4))) float f4v;

#define NU 150000
#define NI 50000
#define NTOT 200000
#define KU 524
#define KUP 576
#define KI 1292
#define KIP 1344

__device__ __forceinline__ f4v ld4(const float* p) { return *(const f4v*)p; }

__device__ __forceinline__ unsigned short bf16r(float x) {
    unsigned u = __float_as_uint(x);
    u += 0x7fff + ((u >> 16) & 1);
    return (unsigned short)(u >> 16);
}
__device__ __forceinline__ unsigned pk2(float lo, float hi) {
    unsigned a = __float_as_uint(lo), b = __float_as_uint(hi);
    a += 0x7fff + ((a >> 16) & 1);
    b += 0x7fff + ((b >> 16) & 1);
    return (a >> 16) | (b & 0xffff0000u);
}
__device__ __forceinline__ float bfu(unsigned short u) {
    return __uint_as_float((unsigned)u << 16);
}

// W [K][64] fp32 -> WT [64][Kpad] bf16 (zero-padded K)
__global__ void prep_wt(const float* __restrict__ src, unsigned short* __restrict__ dst,
                        int K, int Kpad) {
    const int c = blockIdx.y;
    const int k = blockIdx.x * 256 + threadIdx.x;
    if (k >= Kpad) return;
    dst[(size_t)c * Kpad + k] = (k < K) ? bf16r(src[(size_t)k * 64 + c]) : (unsigned short)0;
}

// ---------------------------------------------------------------------------
// Text-mean pre-pass, wave-per-node layout (R8, proven).
// ---------------------------------------------------------------------------
__global__ __launch_bounds__(256, 8) void txt_mean_kernel(
    const float* __restrict__ word_emb,
    const int* __restrict__ u_text_idx, const int* __restrict__ i_text_idx,
    unsigned short* __restrict__ stage)
{
    __shared__ __align__(16) unsigned short st[4][96];   // contiguous 768B
    const int wid  = threadIdx.x >> 6;
    const int lane = threadIdx.x & 63;
    const int node = blockIdx.x * 4 + wid;               // grid exact: NTOT/4
    const int c = lane & 31, h = lane >> 5;
    const int* tip = (node < NU) ? (u_text_idx + (size_t)node * 24)
                                 : (i_text_idx + (size_t)(node - NU) * 24);
    float s[3];
    #pragma unroll
    for (int f = 0; f < 3; ++f) {
        float a = 0.f;
        #pragma unroll
        for (int rr = 0; rr < 4; ++rr) {
            const int idx = tip[f * 8 + rr * 2 + h];     // 32-lane broadcast load
            a += word_emb[(size_t)idx * 32 + c];         // half-wave = full row
        }
        s[f] = a;
    }
    #pragma unroll
    for (int f = 0; f < 3; ++f) s[f] += __shfl_xor(s[f], 32, 64);
    if (h == 0) {
        #pragma unroll
        for (int f = 0; f < 3; ++f) st[wid][f * 32 + c] = bf16r(s[f] * 0.125f);
    }
    __syncthreads();
    if (threadIdx.x < 48) {
        const uint4 v = *(const uint4*)&st[0][threadIdx.x * 8];
        *(uint4*)(stage + (size_t)blockIdx.x * 384 + threadIdx.x * 8) = v;
    }
}

// ---------------------------------------------------------------------------
// Node-feature build + projection (R8 2-barrier pipeline) with CONTIGUOUS
// staging lane-map: instr i covers rows i*16+(t>>4), chunk (t&15)*4 ->
// 4 rows x 256B fully contiguous per instruction (~8 lines vs 32 before).
// ---------------------------------------------------------------------------
__global__ __launch_bounds__(256, 6) void node_init_kernel(
    const float* __restrict__ id_emb, const float* __restrict__ feat_table,
    const unsigned short* __restrict__ txt_stage, const float* __restrict__ numeric,
    const float* __restrict__ wordvec, const float* __restrict__ sentence,
    const int* __restrict__ feat_idx,
    const unsigned short* __restrict__ WT, const float* __restrict__ projb,
    const float* __restrict__ numW, const float* __restrict__ numb,
    unsigned short* __restrict__ x_out, int n, int Ktot, int Kpad, int row_off)
{
    __shared__ __align__(16) unsigned short aS[64][72];
    __shared__ unsigned short fiS[64][5];
    __shared__ float nmrS[64][10];

    const int t = threadIdx.x;
    const int row0 = blockIdx.x * 64;

    for (int e = t; e < 64 * 5; e += 256) {
        const int r = e / 5, j = e - r * 5, row = row0 + r;
        fiS[r][j] = (row < n) ? (unsigned short)feat_idx[row * 5 + j] : (unsigned short)0;
    }
    for (int e = t; e < 64 * 10; e += 256) {
        const int r = e / 10, j = e - r * 10, row = row0 + r;
        nmrS[r][j] = (row < n) ? numeric[(size_t)row * 10 + j] : 0.f;
    }
    __syncthreads();

    const int ch  = (t & 15) * 4;      // float offset within k-tile (contiguous lanes)
    const int rsub = t >> 4;           // row-sub within 16-row group

    const int lane = t & 63;
    const int w16 = (t >> 6) * 16;
    const int l15 = lane & 15;
    const int hi8 = (lane >> 4) * 8;
    const int g4  = (lane >> 4) * 4;

    f32x4 acc[4];
    #pragma unroll
    for (int ct = 0; ct < 4; ++ct) acc[ct] = (f32x4){0.f, 0.f, 0.f, 0.f};

    f4v vals[4];
    auto load_tile = [&](int kt) {
        const int k4 = kt * 64 + ch;
        #pragma unroll
        for (int i = 0; i < 4; ++i) {
            const int r = i * 16 + rsub;       // block-local row
            const int row = row0 + r;
            f4v v = (f4v){0.f, 0.f, 0.f, 0.f};
            if (row < n && k4 < Ktot) {
                if (k4 >= 524) {
                    v = ld4(sentence + (size_t)row * 768 + (k4 - 524));
                } else if (k4 >= 224) {
                    v = ld4(wordvec + (size_t)row * 300 + (k4 - 224));
                } else if (k4 >= 128) {
                    const ushort4 q = *(const ushort4*)(txt_stage
                                        + (size_t)(row_off + row) * 96 + (k4 - 128));
                    v.x = bfu(q.x); v.y = bfu(q.y); v.z = bfu(q.z); v.w = bfu(q.w);
                } else if (k4 >= 64) {
                    const int c = k4 - 64;
                    f4v s = (f4v){0.f, 0.f, 0.f, 0.f};
                    #pragma unroll
                    for (int m = 0; m < 5; ++m) {
                        const f4v g = ld4(feat_table + (size_t)fiS[r][m] * 64 + c);
                        s.x += g.x; s.y += g.y; s.z += g.z; s.w += g.w;
                    }
                    v.x = s.x * 0.2f; v.y = s.y * 0.2f;
                    v.z = s.z * 0.2f; v.w = s.w * 0.2f;
                } else {
                    v = ld4(id_emb + (size_t)row * 64 + k4);
                }
            }
            vals[i] = v;
        }
    };

    const int NT = Kpad / 64;
    load_tile(0);
    for (int kt = 0; kt < NT; ++kt) {
        __syncthreads();   // previous tile's MFMA readers done
        #pragma unroll
        for (int i = 0; i < 4; ++i) {
            const int r = i * 16 + rsub;
            uint2 pk;
            pk.x = pk2(vals[i].x, vals[i].y);
            pk.y = pk2(vals[i].z, vals[i].w);
            *(uint2*)&aS[r][ch] = pk;
        }
        __syncthreads();   // tile visible
        if (kt + 1 < NT) load_tile(kt + 1);   // prefetch, hidden under MFMA
        #pragma unroll
        for (int ks = 0; ks < 2; ++ks) {
            const bf16x8 af = *(const bf16x8*)&aS[w16 + l15][ks * 32 + hi8];
            #pragma unroll
            for (int ct = 0; ct < 4; ++ct) {
                const bf16x8 bfr = *(const bf16x8*)&WT[(size_t)(ct * 16 + l15) * Kpad
                                                      + kt * 64 + ks * 32 + hi8];
                acc[ct] = __builtin_amdgcn_mfma_f32_16x16x32_bf16(af, bfr, acc[ct], 0, 0, 0);
            }
        }
    }

    // epilogue: proj bias + numeric side-GEMM + num bias, write bf16 (cached)
    #pragma unroll
    for (int ct = 0; ct < 4; ++ct) {
        const int c = ct * 16 + l15;
        const float pb = projb[c] + numb[c];
        float wn[10];
        #pragma unroll
        for (int m = 0; m < 10; ++m) wn[m] = numW[m * 64 + c];
        #pragma unroll
        for (int j = 0; j < 4; ++j) {
            const int r = w16 + g4 + j;
            const int row = row0 + r;
            if (row < n) {
                float s = acc[ct][j] + pb;
                #pragma unroll
                for (int m = 0; m < 10; ++m) s += nmrS[r][m] * wn[m];
                x_out[(size_t)(row_off + row) * 64 + c] = bf16r(s);
            }
        }
    }
}

// ---------------------------------------------------------------------------
// GNN layer via MFMA. 64 rows/block. (unchanged from the 503us R8 config)
// ---------------------------------------------------------------------------
__global__ __launch_bounds__(256, 6) void gnn_layer_kernel(
    const unsigned short* __restrict__ x, const int* __restrict__ nbr,
    const unsigned short* __restrict__ VT, const unsigned short* __restrict__ W2T,
    const float* __restrict__ vb, const float* __restrict__ wb,
    void* __restrict__ outp, int finalize)
{
    __shared__ __align__(16) unsigned short mS[64][72];
    __shared__ int nbs[64][8];
    const int t = threadIdx.x;
    const int row0 = blockIdx.x * 64;

    for (int e = t; e < 512; e += 256) nbs[e >> 3][e & 7] = nbr[row0 * 8 + e];
    __syncthreads();

    {   // neighbor mean -> mS (bf16)
        const int r = t >> 2, c16 = (t & 3) * 16;
        float s[16];
        #pragma unroll
        for (int i = 0; i < 16; ++i) s[i] = 0.f;
        #pragma unroll
        for (int m = 0; m < 8; ++m) {
            const unsigned short* p = x + (size_t)nbs[r][m] * 64 + c16;
            const uint4 q0 = *(const uint4*)p;
            const uint4 q1 = *(const uint4*)(p + 8);
            s[0] += bfu(q0.x & 0xffff); s[1] += bfu(q0.x >> 16);
            s[2] += bfu(q0.y & 0xffff); s[3] += bfu(q0.y >> 16);
            s[4] += bfu(q0.z & 0xffff); s[5] += bfu(q0.z >> 16);
            s[6] += bfu(q0.w & 0xffff); s[7] += bfu(q0.w >> 16);
            s[8] += bfu(q1.x & 0xffff); s[9] += bfu(q1.x >> 16);
            s[10] += bfu(q1.y & 0xffff); s[11] += bfu(q1.y >> 16);
            s[12] += bfu(q1.z & 0xffff); s[13] += bfu(q1.z >> 16);
            s[14] += bfu(q1.w & 0xffff); s[15] += bfu(q1.w >> 16);
        }
        uint4 o0, o1;
        o0.x = pk2(s[0] * 0.125f, s[1] * 0.125f);
        o0.y = pk2(s[2] * 0.125f, s[3] * 0.125f);
        o0.z = pk2(s[4] * 0.125f, s[5] * 0.125f);
        o0.w = pk2(s[6] * 0.125f, s[7] * 0.125f);
        o1.x = pk2(s[8] * 0.125f, s[9] * 0.125f);
        o1.y = pk2(s[10] * 0.125f, s[11] * 0.125f);
        o1.z = pk2(s[12] * 0.125f, s[13] * 0.125f);
        o1.w = pk2(s[14] * 0.125f, s[15] * 0.125f);
        *(uint4*)&mS[r][c16] = o0;
        *(uint4*)&mS[r][c16 + 8] = o1;
    }
    __syncthreads();

    const int lane = t & 63;
    const int w16 = (t >> 6) * 16;
    const int l15 = lane & 15;
    const int hi8 = (lane >> 4) * 8;
    const int g4  = (lane >> 4) * 4;

    // agg = nm @ vW
    f32x4 ag[4];
    #pragma unroll
    for (int ct = 0; ct < 4; ++ct) ag[ct] = (f32x4){0.f, 0.f, 0.f, 0.f};
    #pragma unroll
    for (int ks = 0; ks < 2; ++ks) {
        const bf16x8 af = *(const bf16x8*)&mS[w16 + l15][ks * 32 + hi8];
        #pragma unroll
        for (int ct = 0; ct < 4; ++ct) {
            const bf16x8 bfr = *(const bf16x8*)&VT[(ct * 16 + l15) * 64 + ks * 32 + hi8];
            ag[ct] = __builtin_amdgcn_mfma_f32_16x16x32_bf16(af, bfr, ag[ct], 0, 0, 0);
        }
    }
    __syncthreads();   // nm readers done
    #pragma unroll
    for (int ct = 0; ct < 4; ++ct) {
        const int c = ct * 16 + l15;
        const float b = vb[c];
        #pragma unroll
        for (int j = 0; j < 4; ++j)
            mS[w16 + g4 + j][c] = bf16r(ag[ct][j] + b);
    }
    __syncthreads();

    // out = [x | ag] @ wW
    f32x4 acc[4];
    #pragma unroll
    for (int ct = 0; ct < 4; ++ct) acc[ct] = (f32x4){0.f, 0.f, 0.f, 0.f};
    #pragma unroll
    for (int ks = 0; ks < 4; ++ks) {
        bf16x8 af;
        if (ks < 2) af = *(const bf16x8*)&x[(size_t)(row0 + w16 + l15) * 64 + ks * 32 + hi8];
        else        af = *(const bf16x8*)&mS[w16 + l15][(ks - 2) * 32 + hi8];
        #pragma unroll
        for (int ct = 0; ct < 4; ++ct) {
            const bf16x8 bfr = *(const bf16x8*)&W2T[(ct * 16 + l15) * 128 + ks * 32 + hi8];
            acc[ct] = __builtin_amdgcn_mfma_f32_16x16x32_bf16(af, bfr, acc[ct], 0, 0, 0);
        }
    }

    if (!finalize) {
        unsigned short* xo = (unsigned short*)outp;
        #pragma unroll
        for (int ct = 0; ct < 4; ++ct) {
            const int c = ct * 16 + l15;
            const float b = wb[c];
            #pragma unroll
            for (int j = 0; j < 4; ++j)
                xo[(size_t)(row0 + w16 + g4 + j) * 64 + c] = bf16r(fmaxf(acc[ct][j] + b, 0.f));
        }
    } else {
        float* fo = (float*)outp;
        float vc[4][4], ss[4];
        #pragma unroll
        for (int j = 0; j < 4; ++j) ss[j] = 0.f;
        #pragma unroll
        for (int ct = 0; ct < 4; ++ct) {
            const float b = wb[ct * 16 + l15];
            #pragma unroll
            for (int j = 0; j < 4; ++j) {
                vc[ct][j] = acc[ct][j] + b;
                ss[j] += vc[ct][j] * vc[ct][j];
            }
        }
        #pragma unroll
        for (int m = 1; m < 16; m <<= 1) {
            #pragma unroll
            for (int j = 0; j < 4; ++j) ss[j] += __shfl_xor(ss[j], m, 64);
        }
        #pragma unroll
        for (int j = 0; j < 4; ++j) ss[j] = 1.f / fmaxf(sqrtf(ss[j]), 1e-12f);
        #pragma unroll
        for (int ct = 0; ct < 4; ++ct) {
            const int c = ct * 16 + l15;
            #pragma unroll
            for (int j = 0; j < 4; ++j)
                fo[(size_t)(row0 + w16 + g4 + j) * 64 + c] = vc[ct][j] * ss[j];
        }
    }
}

extern "C" void kernel_launch(void* const* d_in, const int* in_sizes, int n_in,
                              void* d_out, int out_size, void* d_ws, size_t ws_size,
                              hipStream_t stream) {
    const float* user_id_emb        = (const float*)d_in[0];
    const float* item_id_emb        = (const float*)d_in[1];
    const float* user_feat_table    = (const float*)d_in[2];
    const float* item_feat_table    = (const float*)d_in[3];
    const float* word_emb           = (const float*)d_in[4];
    const float* user_numeric       = (const float*)d_in[5];
    const float* item_numeric       = (const float*)d_in[6];
    const float* user_word_embedding= (const float*)d_in[7];
    const float* item_word_embedding= (const float*)d_in[8];
    const float* item_sentence_emb  = (const float*)d_in[9];
    const float* user_num_W         = (const float*)d_in[10];
    const float* user_num_b         = (const float*)d_in[11];
    const float* item_num_W         = (const float*)d_in[12];
    const float* item_num_b         = (const float*)d_in[13];
    const float* user_proj_W        = (const float*)d_in[14];
    const float* user_proj_b        = (const float*)d_in[15];
    const float* item_proj_W        = (const float*)d_in[16];
    const float* item_proj_b        = (const float*)d_in[17];
    const float* w_W                = (const float*)d_in[18];
    const float* w_b                = (const float*)d_in[19];
    const float* v_W                = (const float*)d_in[20];
    const float* v_b                = (const float*)d_in[21];
    const int*   user_feat_idx      = (const int*)d_in[22];
    const int*   item_feat_idx      = (const int*)d_in[23];
    const int*   user_text_idx      = (const int*)d_in[24];
    const int*   item_text_idx      = (const int*)d_in[25];
    const int*   neighbors          = (const int*)d_in[26];

    // ws layout (bf16): x0 [NTOT][64], x1 [NTOT][64]
    unsigned short* x0 = (unsigned short*)d_ws;
    unsigned short* x1 = x0 + (size_t)NTOT * 64;

    // d_out FRONT: text-mean staging [NTOT][96] bf16 (38.4 MB)
    unsigned short* txt_stage = (unsigned short*)d_out;
    // d_out TAIL: bf16 weights (270 KB)
    const size_t prep_bytes = 2ull * 64 * (KUP + KIP + 64 + 128);
    char* WTbase = (char*)d_out + (size_t)out_size * 4 - prep_bytes;
    unsigned short* WTu = (unsigned short*)WTbase;
    unsigned short* WTi = WTu + 64 * KUP;
    unsigned short* VT0 = WTi + 64 * KIP;
    unsigned short* W20 = VT0 + 64 * 64;
    // layer-1 weights re-prepped into dead x0 region after L0
    unsigned short* VT1 = (unsigned short*)d_ws;
    unsigned short* W21 = VT1 + 64 * 64;

    prep_wt<<<dim3((KUP + 255) / 256, 64), 256, 0, stream>>>(user_proj_W, WTu, KU, KUP);
    prep_wt<<<dim3((KIP + 255) / 256, 64), 256, 0, stream>>>(item_proj_W, WTi, KI, KIP);
    prep_wt<<<dim3(1, 64), 256, 0, stream>>>(v_W, VT0, 64, 64);
    prep_wt<<<dim3(1, 64), 256, 0, stream>>>(w_W, W20, 128, 128);

    // text-mean pre-pass (wave-per-node coalesced gather)
    txt_mean_kernel<<<NTOT / 4, 256, 0, stream>>>(
        word_emb, user_text_idx, item_text_idx, txt_stage);

    node_init_kernel<<<(NU + 63) / 64, 256, 0, stream>>>(
        user_id_emb, user_feat_table, txt_stage, user_numeric,
        user_word_embedding, nullptr, user_feat_idx,
        WTu, user_proj_b, user_num_W, user_num_b, x0, NU, KU, KUP, 0);
    node_init_kernel<<<(NI + 63) / 64, 256, 0, stream>>>(
        item_id_emb, item_feat_table, txt_stage, item_numeric,
        item_word_embedding, item_sentence_emb, item_feat_idx,
        WTi, item_proj_b, item_num_W, item_num_b, x0, NI, KI, KIP, NU);

    // layer 0: x0 -> x1 (relu, bf16)
    gnn_layer_kernel<<<NTOT / 64, 256, 0, stream>>>(
        x0, neighbors, VT0, W20, v_b, w_b, x1, 0);

    // re-prep layer-1 weights into dead x0 region
    prep_wt<<<dim3(1, 64), 256, 0, stream>>>(v_W + 64 * 64, VT1, 64, 64);
    prep_wt<<<dim3(1, 64), 256, 0, stream>>>(w_W + 128 * 64, W21, 128, 128);

    // layer 1 + fused normalize: x1 -> d_out (fp32, overwrites staging+weights)
    gnn_layer_kernel<<<NTOT / 64, 256, 0, stream>>>(
        x1, neighbors, VT1, W21, v_b + 64, w_b + 64, d_out, 1);
}